// Round 14
// baseline (362.069 us; speedup 1.0000x reference)
//
#include <hip/hip_runtime.h>

#define HH 128
#define WW 256
#define DEPTH 4          // ring slots (>= AHEAD+1)
#define AHEAD 3          // channel-pairs in flight
#define NCP 32           // 64 channels -> 32 channel-pairs
#define PLANE 32768      // H*W dwords per plane
#define PACKED_DWORDS 4194304ull   // packed S: 4 b * 32 cp * 32768
#define ZOFF PACKED_DWORDS         // zero region: 1024 dwords after packed S

typedef unsigned int u32;
typedef _Float16 f16;
typedef f16 f16x2 __attribute__((ext_vector_type(2)));
typedef u32 u32x4 __attribute__((ext_vector_type(4)));

union U32H2 { u32 u; f16x2 h; };

__device__ __forceinline__ void gload_lds16(const u32* g, u32* l) {
  __builtin_amdgcn_global_load_lds(
      (const __attribute__((address_space(1))) u32*)g,
      (__attribute__((address_space(3))) u32*)l, 16, 0, 0);
}

__device__ __forceinline__ void waitvN(int n) {  // n compile-time after unroll
  if      (n >= 8) asm volatile("s_waitcnt vmcnt(8)" ::: "memory");
  else if (n == 6) asm volatile("s_waitcnt vmcnt(6)" ::: "memory");
  else if (n == 4) asm volatile("s_waitcnt vmcnt(4)" ::: "memory");
  else if (n == 3) asm volatile("s_waitcnt vmcnt(3)" ::: "memory");
  else             asm volatile("s_waitcnt vmcnt(0)" ::: "memory");
}

// ---- zero the 4 KB OOB-source region of ws ----
__global__ void zero_ws(u32* z) { ((float4*)z)[threadIdx.x] = make_float4(0,0,0,0); }

// ---- pack S only: fp32 [b][c][h][w] -> dword=half2(c,c+1) at [b][c/2][h][w] ----
__global__ __launch_bounds__(256) void pack_s(
    const float* __restrict__ src, u32* __restrict__ dst)
{
  const int di  = blockIdx.x * 1024 + threadIdx.x * 4;
  const int p   = di & (PLANE - 1);
  const int cpb = di >> 15;
  const int bI  = cpb >> 5, cp = cpb & 31;
  const size_t s0 = ((size_t)(bI * 64 + cp * 2)) * PLANE + p;
  const float4 x = *(const float4*)(src + s0);
  const float4 y = *(const float4*)(src + s0 + PLANE);
  U32H2 h0, h1, h2, h3;
  h0.h = f16x2{(f16)x.x, (f16)y.x};
  h1.h = f16x2{(f16)x.y, (f16)y.y};
  h2.h = f16x2{(f16)x.z, (f16)y.z};
  h3.h = f16x2{(f16)x.w, (f16)y.w};
  *(u32x4*)(dst + di) = (u32x4){h0.u, h1.u, h2.u, h3.u};
}

// ---- dy-paired inner loop. NDY=2: dy0,dy0+1 share one F load. ----
template<int NDY>
__device__ __forceinline__ void corr_loop(
    const u32* sg0, const u32* sg1, size_t st0, size_t st1,
    const float* fg, u32* Sl, int l4, float* obase)
{
  float acc[NDY * 36];
#pragma unroll
  for (int k = 0; k < NDY * 36; ++k) acc[k] = 0.f;

  float4 frx[DEPTH], fry[DEPTH];            // F ring (fp32), compile-time idx
  constexpr int L = NDY + 2;                // vmem per pair

#define PAIRI(cp) do {                                            \
    const int sl = (cp) & 3;                                      \
    gload_lds16(sg0, Sl + (sl * 2 + 0) * 264 + 4); sg0 += st0;    \
    if (NDY == 2) { gload_lds16(sg1, Sl + (sl * 2 + 1) * 264 + 4); sg1 += st1; } \
    frx[sl] = *(const float4*)fg;                                 \
    fry[sl] = *(const float4*)(fg + PLANE);                       \
    fg += 2 * PLANE;                                              \
  } while (0)

  PAIRI(0); PAIRI(1); PAIRI(2);             // AHEAD pairs in flight

#pragma unroll
  for (int cp = 0; cp < NCP; ++cp) {
    const int rem = NCP - 1 - cp;
    waitvN(L * (rem < AHEAD - 1 ? rem : AHEAD - 1));  // drain pair cp only
    __builtin_amdgcn_sched_barrier(0);      // rule 18: no ds_read above the wait
    const int sl = cp & 3;

    U32H2 f_[4];                            // RNE fp32->f16 pack of F
    f_[0].h = f16x2{(f16)frx[sl].x, (f16)fry[sl].x};
    f_[1].h = f16x2{(f16)frx[sl].y, (f16)fry[sl].y};
    f_[2].h = f16x2{(f16)frx[sl].z, (f16)fry[sl].z};
    f_[3].h = f16x2{(f16)frx[sl].w, (f16)fry[sl].w};

    u32x4 s0[NDY], s1[NDY], s2[NDY];
#pragma unroll
    for (int k = 0; k < NDY; ++k) {
      const u32* R = Sl + (sl * 2 + k) * 264 + l4;
      s0[k] = *(const u32x4*)(R);           // w-4..w-1 (pads at edges)
      s1[k] = *(const u32x4*)(R + 4);       // w..w+3
      s2[k] = *(const u32x4*)(R + 8);       // w+4..w+7
    }
    if (cp + AHEAD < NCP) PAIRI(cp + AHEAD);

#pragma unroll
    for (int k = 0; k < NDY; ++k) {
      U32H2 s_[12];
#pragma unroll
      for (int j = 0; j < 4; ++j) {
        s_[j].u = s0[k][j]; s_[j + 4].u = s1[k][j]; s_[j + 8].u = s2[k][j];
      }
#pragma unroll
      for (int dx = 0; dx < 9; ++dx)
#pragma unroll
        for (int i = 0; i < 4; ++i)
          acc[k * 36 + dx * 4 + i] = __builtin_amdgcn_fdot2(
              f_[i].h, s_[i + dx].h, acc[k * 36 + dx * 4 + i], false);
    }
  }
#undef PAIRI

  const float sc = 1.0f / 64.0f;
#pragma unroll
  for (int k = 0; k < NDY; ++k)
#pragma unroll
    for (int dx = 0; dx < 9; ++dx) {
      float4 v = make_float4(acc[k * 36 + dx * 4 + 0] * sc,
                             acc[k * 36 + dx * 4 + 1] * sc,
                             acc[k * 36 + dx * 4 + 2] * sc,
                             acc[k * 36 + dx * 4 + 3] * sc);
      *(float4*)(obase + (size_t)(k * 9 + dx) * PLANE) = v;
    }
}

// ---- correlation: block=(b,h), 5 waves, wave = dy pair {2w, 2w+1} ----
__global__ __launch_bounds__(320, 3) void corr_f16(
    const u32* __restrict__ ps, const float* __restrict__ first,
    const u32* __restrict__ zws, float* __restrict__ out)
{
  __shared__ u32 lds[5][DEPTH * 2 * 264];   // 42240 B/block

  const int tid  = threadIdx.x;
  const int lane = tid & 63;
  const int wv   = __builtin_amdgcn_readfirstlane(tid >> 6);  // 0..4
  const int bid  = blockIdx.x;
  const int xcd  = bid & 7;                 // contiguous 16-row h band per XCD
  const int idx  = bid >> 3;                // 0..63
  const int h    = xcd * 16 + (idx & 15);
  const int b    = idx >> 4;                // 0..3
  const int l4   = lane * 4;
  const int dy0  = 2 * wv;                  // wv==4 -> dy 8 only

  u32* Sl = &lds[wv][0];                    // 4 slots x 2 rows x [4|256|4]
  {                                         // zero side pads once (wave-private)
    const int sl = lane >> 4, row = (lane >> 3) & 1, pd = lane & 7;
    Sl[(sl * 2 + row) * 264 + (pd < 4 ? pd : 256 + pd)] = 0;
  }

  const int gh0 = h + dy0 - 4, gh1 = gh0 + 1;
  const bool ok0 = (0 <= gh0 && gh0 < HH), ok1 = (0 <= gh1 && gh1 < HH);
  const u32* sbase = ps + (size_t)(b * NCP) * PLANE;
  // OOB rows read from the zeroed ws region with stride 0 (stay in 4 KB).
  const u32* sg0 = ok0 ? sbase + (size_t)gh0 * WW + l4 : zws + l4;
  const u32* sg1 = ok1 ? sbase + (size_t)gh1 * WW + l4 : zws + l4;
  const size_t st0 = ok0 ? PLANE : 0, st1 = ok1 ? PLANE : 0;

  const float* fg = first + (size_t)(b * 64) * PLANE + (size_t)h * WW + l4;
  float* obase = out + (((size_t)(b * 81 + dy0 * 9)) * HH + h) * WW + l4;

  if (wv < 4) corr_loop<2>(sg0, sg1, st0, st1, fg, Sl, l4, obase);
  else        corr_loop<1>(sg0, sg1, st0, st1, fg, Sl, l4, obase);
}

// ---- fallback (proven-correct fp32 path) if ws is too small ----
__global__ __launch_bounds__(576) void corr_fp32_fb(
    const float* __restrict__ first, const float* __restrict__ second,
    float* __restrict__ out)
{
  const int tid  = threadIdx.x;
  const int lane = tid & 63;
  const int wv   = tid >> 6;
  const int bid  = blockIdx.x;
  const int idx  = bid >> 3;
  const int h    = (bid & 7) * 16 + (idx & 15);
  const int b    = idx >> 4;
  const int l4   = lane * 4;
  const size_t plane = (size_t)HH * WW;
  float* obase = out + (((size_t)b * 81 + (size_t)wv * 9) * HH + h) * WW + l4;
  const int gh = h + wv - 4;
  if (gh < 0 || gh >= HH) {
    const float4 z = make_float4(0.f, 0.f, 0.f, 0.f);
#pragma unroll
    for (int dx = 0; dx < 9; ++dx) *(float4*)(obase + (size_t)dx * plane) = z;
    return;
  }
  const float* frow = first  + ((size_t)b * 64 * HH + h ) * WW;
  const float* srow = second + ((size_t)b * 64 * HH + gh) * WW;
  const bool zL = (lane == 0), zR = (lane == 63);
  const int offL = zL ? l4 : l4 - 4;
  const int offR = zR ? l4 : l4 + 4;
  float acc[9][4];
#pragma unroll
  for (int dx = 0; dx < 9; ++dx)
#pragma unroll
    for (int i = 0; i < 4; ++i) acc[dx][i] = 0.f;
#pragma unroll 2
  for (int c = 0; c < 64; ++c) {
    const size_t cp = (size_t)c * plane;
    float4 f  = *(const float4*)(frow + cp + l4);
    float4 aL = *(const float4*)(srow + cp + offL);
    float4 aM = *(const float4*)(srow + cp + l4);
    float4 aR = *(const float4*)(srow + cp + offR);
    if (zL) { aL.x = aL.y = aL.z = aL.w = 0.f; }
    if (zR) { aR.x = aR.y = aR.z = aR.w = 0.f; }
    const float fv[4]  = {f.x, f.y, f.z, f.w};
    const float sv[12] = {aL.x, aL.y, aL.z, aL.w, aM.x, aM.y, aM.z, aM.w,
                          aR.x, aR.y, aR.z, aR.w};
#pragma unroll
    for (int dx = 0; dx < 9; ++dx)
#pragma unroll
      for (int i = 0; i < 4; ++i)
        acc[dx][i] = fmaf(fv[i], sv[i + dx], acc[dx][i]);
  }
  const float sc = 1.0f / 64.0f;
#pragma unroll
  for (int dx = 0; dx < 9; ++dx) {
    float4 v = make_float4(acc[dx][0] * sc, acc[dx][1] * sc,
                           acc[dx][2] * sc, acc[dx][3] * sc);
    *(float4*)(obase + (size_t)dx * plane) = v;
  }
}

extern "C" void kernel_launch(void* const* d_in, const int* in_sizes, int n_in,
                              void* d_out, int out_size, void* d_ws, size_t ws_size,
                              hipStream_t stream) {
  const float* first  = (const float*)d_in[0];
  const float* second = (const float*)d_in[1];
  float* out = (float*)d_out;
  (void)in_sizes; (void)n_in; (void)out_size;

  if (ws_size >= (PACKED_DWORDS + 1024) * 4ull) {
    u32* psecond = (u32*)d_ws;
    u32* zws = psecond + ZOFF;
    zero_ws <<<dim3(1),    dim3(256), 0, stream>>>(zws);
    pack_s  <<<dim3(4096), dim3(256), 0, stream>>>(second, psecond);
    corr_f16<<<dim3(512),  dim3(320), 0, stream>>>(psecond, first, zws, out);
  } else {
    corr_fp32_fb<<<dim3(512), dim3(576), 0, stream>>>(first, second, out);
  }
}

// Round 15
// 40.018 us; speedup vs baseline: 9.0477x; 9.0477x over previous
//
#include <hip/hip_runtime.h>

#define HH 128
#define WW 256
#define NCP 32           // 64 channels -> 32 channel-pairs
#define PLANE 32768      // H*W dwords per plane
#define PACKED_DWORDS 4194304ull   // packed S: 4 b * 32 cp * 32768
#define ZOFF PACKED_DWORDS         // zero region: 1024 dwords after packed S

typedef unsigned int u32;
typedef _Float16 f16;
typedef f16 f16x2 __attribute__((ext_vector_type(2)));
typedef u32 u32x4 __attribute__((ext_vector_type(4)));

union U32H2 { u32 u; f16x2 h; };

__device__ __forceinline__ void gload_lds16(const u32* g, u32* l) {
  __builtin_amdgcn_global_load_lds(
      (const __attribute__((address_space(1))) u32*)g,
      (__attribute__((address_space(3))) u32*)l, 16, 0, 0);
}

// ---- pack S + zero the OOB region (block 0) ----
__global__ __launch_bounds__(256) void pack_s(
    const float* __restrict__ src, u32* __restrict__ dst, u32* __restrict__ zws)
{
  if (blockIdx.x == 0)                      // 256 thr x 16B = 4 KB zero region
    ((float4*)zws)[threadIdx.x] = make_float4(0.f, 0.f, 0.f, 0.f);
  const int di  = blockIdx.x * 1024 + threadIdx.x * 4;
  const int p   = di & (PLANE - 1);
  const int cpb = di >> 15;
  const int bI  = cpb >> 5, cp = cpb & 31;
  const size_t s0 = ((size_t)(bI * 64 + cp * 2)) * PLANE + p;
  const float4 x = *(const float4*)(src + s0);
  const float4 y = *(const float4*)(src + s0 + PLANE);
  U32H2 h0, h1, h2, h3;
  h0.h = f16x2{(f16)x.x, (f16)y.x};
  h1.h = f16x2{(f16)x.y, (f16)y.y};
  h2.h = f16x2{(f16)x.z, (f16)y.z};
  h3.h = f16x2{(f16)x.w, (f16)y.w};
  *(u32x4*)(dst + di) = (u32x4){h0.u, h1.u, h2.u, h3.u};
}

// ---- correlation: block=(b,h), 5 waves; wave wv = dy pair {2wv, 2wv+1}.
// One F load pair (rows c,c+1 at height h) feeds BOTH dys -> 20 vmem issues
// per block-cp for 9 dys (vs 27 unpaired). wv=4 computes dy=9 and discards.
__global__ __launch_bounds__(320, 2) void corr_f16(
    const u32* __restrict__ ps, const float* __restrict__ first,
    const u32* __restrict__ zws, float* __restrict__ out)
{
  __shared__ u32 lds[5][8 * 264];           // 4 slots x 2 rows x [4|256|4]; 42240 B

  const int tid  = threadIdx.x;
  const int lane = tid & 63;
  const int wv   = __builtin_amdgcn_readfirstlane(tid >> 6);  // 0..4
  const int bid  = blockIdx.x;
  const int xcd  = bid & 7;                 // contiguous 16-row h band per XCD
  const int idx  = bid >> 3;                // 0..63
  const int h    = xcd * 16 + (idx & 15);
  const int b    = idx >> 4;                // 0..3
  const int l4   = lane * 4;
  const int dy0  = 2 * wv;

  u32* Sl = &lds[wv][0];
  {                                         // zero side pads once (wave-private)
    const int sl = lane >> 4, row = (lane >> 3) & 1, pd = lane & 7;
    Sl[(sl * 2 + row) * 264 + (pd < 4 ? pd : 256 + pd)] = 0;
  }

  const int gh0 = h + dy0 - 4, gh1 = gh0 + 1;
  const bool ok0 = (0 <= gh0 && gh0 < HH), ok1 = (0 <= gh1 && gh1 < HH);
  const u32* sbase = ps + (size_t)(b * NCP) * PLANE;
  const u32* sg0 = ok0 ? sbase + (size_t)gh0 * WW + l4 : zws + l4;
  const u32* sg1 = ok1 ? sbase + (size_t)gh1 * WW + l4 : zws + l4;
  const size_t st0 = ok0 ? PLANE : 0, st1 = ok1 ? PLANE : 0;
  const float* fg = first + (size_t)(b * 64) * PLANE + (size_t)h * WW + l4;
  float* ob = out + (size_t)(b * 81 + dy0 * 9) * PLANE + (size_t)h * WW + l4;

  float4 frx[4], fry[4];                    // F ring, literal indices only
  float acc[72];
#pragma unroll
  for (int k = 0; k < 72; ++k) acc[k] = 0.f;

#define PAIRI(sl) do {                                            \
    gload_lds16(sg0, Sl + ((sl) * 2 + 0) * 264 + 4); sg0 += st0;  \
    gload_lds16(sg1, Sl + ((sl) * 2 + 1) * 264 + 4); sg1 += st1;  \
    frx[sl] = *(const float4*)fg;                                 \
    fry[sl] = *(const float4*)(fg + PLANE);                       \
    fg += 2 * (size_t)PLANE;                                      \
  } while (0)

  PAIRI(0); PAIRI(1); PAIRI(2);             // 3 pairs = 12 vmem in flight

  // One iteration; j is a LITERAL ring slot (0..3) -> no runtime indexing.
#define ITER(j, WN, DOP) do {                                     \
    if      ((WN) == 8) asm volatile("s_waitcnt vmcnt(8)" ::: "memory"); \
    else if ((WN) == 4) asm volatile("s_waitcnt vmcnt(4)" ::: "memory"); \
    else                asm volatile("s_waitcnt vmcnt(0)" ::: "memory"); \
    __builtin_amdgcn_sched_barrier(0);                            \
    U32H2 f_[4];                                                  \
    f_[0].h = f16x2{(f16)frx[j].x, (f16)fry[j].x};                \
    f_[1].h = f16x2{(f16)frx[j].y, (f16)fry[j].y};                \
    f_[2].h = f16x2{(f16)frx[j].z, (f16)fry[j].z};                \
    f_[3].h = f16x2{(f16)frx[j].w, (f16)fry[j].w};                \
    const u32* R0 = Sl + ((j) * 2 + 0) * 264 + l4;                \
    const u32* R1 = Sl + ((j) * 2 + 1) * 264 + l4;                \
    const u32x4 a0 = *(const u32x4*)(R0);                         \
    const u32x4 a1 = *(const u32x4*)(R0 + 4);                     \
    const u32x4 a2 = *(const u32x4*)(R0 + 8);                     \
    const u32x4 b0 = *(const u32x4*)(R1);                         \
    const u32x4 b1 = *(const u32x4*)(R1 + 4);                     \
    const u32x4 b2 = *(const u32x4*)(R1 + 8);                     \
    if (DOP) PAIRI(((j) + 3) & 3);                                \
    U32H2 s_[12];                                                 \
    _Pragma("unroll") for (int q = 0; q < 4; ++q) {               \
      s_[q].u = a0[q]; s_[q + 4].u = a1[q]; s_[q + 8].u = a2[q];  \
    }                                                             \
    _Pragma("unroll") for (int dx = 0; dx < 9; ++dx)              \
      _Pragma("unroll") for (int i = 0; i < 4; ++i)               \
        acc[dx * 4 + i] = __builtin_amdgcn_fdot2(                 \
            f_[i].h, s_[i + dx].h, acc[dx * 4 + i], false);       \
    _Pragma("unroll") for (int q = 0; q < 4; ++q) {               \
      s_[q].u = b0[q]; s_[q + 4].u = b1[q]; s_[q + 8].u = b2[q];  \
    }                                                             \
    _Pragma("unroll") for (int dx = 0; dx < 9; ++dx)              \
      _Pragma("unroll") for (int i = 0; i < 4; ++i)               \
        acc[36 + dx * 4 + i] = __builtin_amdgcn_fdot2(            \
            f_[i].h, s_[i + dx].h, acc[36 + dx * 4 + i], false);  \
  } while (0)

#pragma unroll 1
  for (int t = 0; t < 7; ++t) {             // cp = 4t+j, t=0..6 -> cp 0..27
    ITER(0, 8, 1); ITER(1, 8, 1); ITER(2, 8, 1); ITER(3, 8, 1);
  }
  ITER(0, 8, 1);                            // cp=28, issues pair 31
  ITER(1, 8, 0);                            // cp=29
  ITER(2, 4, 0);                            // cp=30
  ITER(3, 0, 0);                            // cp=31
#undef ITER
#undef PAIRI

  const float sc = 1.0f / 64.0f;
#pragma unroll
  for (int dx = 0; dx < 9; ++dx) {
    float4 v = make_float4(acc[dx * 4 + 0] * sc, acc[dx * 4 + 1] * sc,
                           acc[dx * 4 + 2] * sc, acc[dx * 4 + 3] * sc);
    *(float4*)(ob + (size_t)dx * PLANE) = v;
  }
  if (wv < 4) {                             // dy1 = dy0+1 <= 8: write it
#pragma unroll
    for (int dx = 0; dx < 9; ++dx) {
      float4 v = make_float4(acc[36 + dx * 4 + 0] * sc, acc[36 + dx * 4 + 1] * sc,
                             acc[36 + dx * 4 + 2] * sc, acc[36 + dx * 4 + 3] * sc);
      *(float4*)(ob + (size_t)(9 + dx) * PLANE) = v;
    }
  }
}

// ---- fallback (proven-correct fp32 path) if ws is too small ----
__global__ __launch_bounds__(576) void corr_fp32_fb(
    const float* __restrict__ first, const float* __restrict__ second,
    float* __restrict__ out)
{
  const int tid  = threadIdx.x;
  const int lane = tid & 63;
  const int wv   = tid >> 6;
  const int bid  = blockIdx.x;
  const int idx  = bid >> 3;
  const int h    = (bid & 7) * 16 + (idx & 15);
  const int b    = idx >> 4;
  const int l4   = lane * 4;
  const size_t plane = (size_t)HH * WW;
  float* obase = out + (((size_t)b * 81 + (size_t)wv * 9) * HH + h) * WW + l4;
  const int gh = h + wv - 4;
  if (gh < 0 || gh >= HH) {
    const float4 z = make_float4(0.f, 0.f, 0.f, 0.f);
#pragma unroll
    for (int dx = 0; dx < 9; ++dx) *(float4*)(obase + (size_t)dx * plane) = z;
    return;
  }
  const float* frow = first  + ((size_t)b * 64 * HH + h ) * WW;
  const float* srow = second + ((size_t)b * 64 * HH + gh) * WW;
  const bool zL = (lane == 0), zR = (lane == 63);
  const int offL = zL ? l4 : l4 - 4;
  const int offR = zR ? l4 : l4 + 4;
  float acc[9][4];
#pragma unroll
  for (int dx = 0; dx < 9; ++dx)
#pragma unroll
    for (int i = 0; i < 4; ++i) acc[dx][i] = 0.f;
#pragma unroll 2
  for (int c = 0; c < 64; ++c) {
    const size_t cp = (size_t)c * plane;
    float4 f  = *(const float4*)(frow + cp + l4);
    float4 aL = *(const float4*)(srow + cp + offL);
    float4 aM = *(const float4*)(srow + cp + l4);
    float4 aR = *(const float4*)(srow + cp + offR);
    if (zL) { aL.x = aL.y = aL.z = aL.w = 0.f; }
    if (zR) { aR.x = aR.y = aR.z = aR.w = 0.f; }
    const float fv[4]  = {f.x, f.y, f.z, f.w};
    const float sv[12] = {aL.x, aL.y, aL.z, aL.w, aM.x, aM.y, aM.z, aM.w,
                          aR.x, aR.y, aR.z, aR.w};
#pragma unroll
    for (int dx = 0; dx < 9; ++dx)
#pragma unroll
      for (int i = 0; i < 4; ++i)
        acc[dx][i] = fmaf(fv[i], sv[i + dx], acc[dx][i]);
  }
  const float sc = 1.0f / 64.0f;
#pragma unroll
  for (int dx = 0; dx < 9; ++dx) {
    float4 v = make_float4(acc[dx][0] * sc, acc[dx][1] * sc,
                           acc[dx][2] * sc, acc[dx][3] * sc);
    *(float4*)(obase + (size_t)dx * plane) = v;
  }
}

extern "C" void kernel_launch(void* const* d_in, const int* in_sizes, int n_in,
                              void* d_out, int out_size, void* d_ws, size_t ws_size,
                              hipStream_t stream) {
  const float* first  = (const float*)d_in[0];
  const float* second = (const float*)d_in[1];
  float* out = (float*)d_out;
  (void)in_sizes; (void)n_in; (void)out_size;

  if (ws_size >= (PACKED_DWORDS + 1024) * 4ull) {
    u32* psecond = (u32*)d_ws;
    u32* zws = psecond + ZOFF;
    pack_s  <<<dim3(4096), dim3(256), 0, stream>>>(second, psecond, zws);
    corr_f16<<<dim3(512),  dim3(320), 0, stream>>>(psecond, first, zws, out);
  } else {
    corr_fp32_fb<<<dim3(512), dim3(576), 0, stream>>>(first, second, out);
  }
}